// Round 1
// 666.975 us; speedup vs baseline: 1.1731x; 1.1731x over previous
//
#include <hip/hip_runtime.h>
#include <hip/hip_bf16.h>

#define NUM_HEADS 16
#define DM 1024
#define DEPTH 64
#define BB 4
#define SS 1024
#define SL 1023            // S-1
#define M_ROWS (BB*SL)     // 4092

typedef __attribute__((ext_vector_type(8))) short short8;
typedef __attribute__((ext_vector_type(4))) float floatx4;

__device__ inline unsigned short f2bf(float f) {
  __hip_bfloat16 hb = __float2bfloat16(f);
  return *reinterpret_cast<unsigned short*>(&hb);
}
__device__ inline short8 ld_frag(const unsigned short* p) {
  return *reinterpret_cast<const short8*>(p);
}

// async global->LDS, 16 B per lane (wave-uniform base + lane*16 dest)
#define GLDS(g, l) __builtin_amdgcn_global_load_lds( \
    (const __attribute__((address_space(1))) void*)(g), \
    (__attribute__((address_space(3))) void*)(l), 16, 0, 0)

// ---------------- prep kernels ----------------------------------------------
// fp32 -> bf16, 8 elements/thread, contiguous
__global__ __launch_bounds__(256) void f32_to_bf16_vec(
    const float* __restrict__ in, unsigned short* __restrict__ out, int n8)
{
  int i = blockIdx.x * 256 + threadIdx.x;
  if (i >= n8) return;
  const float4 f0 = ((const float4*)in)[(size_t)i * 2];
  const float4 f1 = ((const float4*)in)[(size_t)i * 2 + 1];
  unsigned short t[8];
  t[0]=f2bf(f0.x); t[1]=f2bf(f0.y); t[2]=f2bf(f0.z); t[3]=f2bf(f0.w);
  t[4]=f2bf(f1.x); t[5]=f2bf(f1.y); t[6]=f2bf(f1.z); t[7]=f2bf(f1.w);
  ((uint4*)out)[i] = *(uint4*)t;
}

// W[1024][1024] fp32 -> WT[1024][1024] bf16 with WT[n][k] = W[k][n]
__global__ __launch_bounds__(256) void transpose_to_bf16(
    const float* __restrict__ W, unsigned short* __restrict__ WT)
{
  __shared__ unsigned short tile[64][72];   // pad rows (144 B)
  const int tid = threadIdx.x;
  const int k0 = blockIdx.y * 64, n0 = blockIdx.x * 64;
  {
    const int kl = tid >> 2, nc = (tid & 3) * 16;
    const float* src = W + (size_t)(k0 + kl) * DM + n0 + nc;
    #pragma unroll
    for (int j = 0; j < 16; j += 4) {
      float4 f = *(const float4*)(src + j);
      tile[nc + j + 0][kl] = f2bf(f.x);
      tile[nc + j + 1][kl] = f2bf(f.y);
      tile[nc + j + 2][kl] = f2bf(f.z);
      tile[nc + j + 3][kl] = f2bf(f.w);
    }
  }
  __syncthreads();
  {
    const int nl = tid >> 2, kc = (tid & 3) * 16;
    unsigned short tmp[16];
    #pragma unroll
    for (int j = 0; j < 16; j++) tmp[j] = tile[nl][kc + j];
    unsigned short* dst = WT + (size_t)(n0 + nl) * DM + k0 + kc;
    *(uint4*)&dst[0] = *(uint4*)&tmp[0];
    *(uint4*)&dst[8] = *(uint4*)&tmp[8];
  }
}

// ---------------- GEMM: C[M x 1024] = A[M x 1024] * BT^T + bias -------------
// A bf16 [M][K], BT bf16 [N][K] (pre-transposed). BM=64 BN=128 BK=32.
// 256 thr = 4 waves (2m x 2n), wave tile 32x64 (2x4 frags, 8 MFMA / K-step).
// global_load_lds staging, double-buffered LDS, prefetch next tile before
// compute (T3 minimal 2-phase). LDS k-slots XOR-swizzled: involution
// slot_phys = slot ^ ((row>>1)&3); linear LDS dest + inverse-swizzled source.
template <bool OUT_BF16>
__global__ __launch_bounds__(256) void gemm_bt(
    const unsigned short* __restrict__ A,   // [M][DM] bf16
    const unsigned short* __restrict__ BT,  // [DM][DM] bf16 (n-major)
    const float* __restrict__ bias,
    void* __restrict__ Cv, int M)
{
  constexpr int BM = 64, BN = 128, BK = 32;
  __shared__ __align__(16) unsigned short As[2][BM * BK];   // 4 KB / buf
  __shared__ __align__(16) unsigned short Bs[2][BN * BK];   // 8 KB / buf

  const int tid = threadIdx.x;
  const int w = tid >> 6, lane = tid & 63, q4 = lane >> 4, l16 = lane & 15;
  const int wm = w >> 1, wn = w & 1;
  const int rb = blockIdx.y * BM;
  const int cb = blockIdx.x * BN;

  // --- staging source addresses (constant per thread; advance by k0) ---
  // As: thread t owns LDS bytes [t*16, t*16+16): row = t>>2, slot_lin = t&3
  const int a_row = tid >> 2;
  const int a_slot = (tid & 3) ^ ((a_row >> 1) & 3);
  int a_grow = rb + a_row; if (a_grow >= M) a_grow = M - 1;   // clamp (unused rows)
  const unsigned short* a_src = A + (size_t)a_grow * DM + a_slot * 8;
  // Bs: inst j covers bytes j*4096 + t*16: row = j*64 + (t>>2)
  const int b_row0 = tid >> 2;
  const int b_row1 = 64 + (tid >> 2);
  const int b_slot0 = (tid & 3) ^ ((b_row0 >> 1) & 3);
  const int b_slot1 = (tid & 3) ^ ((b_row1 >> 1) & 3);
  const unsigned short* b_src0 = BT + (size_t)(cb + b_row0) * DM + b_slot0 * 8;
  const unsigned short* b_src1 = BT + (size_t)(cb + b_row1) * DM + b_slot1 * 8;

  // --- fragment read offsets (u16 index, constant) ---
  int aoff[2], boff[4];
  #pragma unroll
  for (int i = 0; i < 2; i++) {
    int r = wm * 32 + i * 16 + l16;
    aoff[i] = r * BK + ((q4 ^ ((r >> 1) & 3)) * 8);
  }
  #pragma unroll
  for (int j = 0; j < 4; j++) {
    int r = wn * 64 + j * 16 + l16;
    boff[j] = r * BK + ((q4 ^ ((r >> 1) & 3)) * 8);
  }

  floatx4 acc[2][4];
  #pragma unroll
  for (int i = 0; i < 2; i++)
    #pragma unroll
    for (int j = 0; j < 4; j++) acc[i][j] = (floatx4){0.f,0.f,0.f,0.f};

  // prologue: stage tile 0
  GLDS(a_src,  &As[0][tid * 8]);
  GLDS(b_src0, &Bs[0][tid * 8]);
  GLDS(b_src1, &Bs[0][2048 + tid * 8]);
  __syncthreads();

  int cur = 0;
  constexpr int NT = DM / BK;   // 32
  for (int t = 0; t < NT; ++t) {
    if (t + 1 < NT) {           // issue next-tile loads; they fly under MFMA
      const int kn = (t + 1) * BK;
      GLDS(a_src + kn,  &As[cur ^ 1][tid * 8]);
      GLDS(b_src0 + kn, &Bs[cur ^ 1][tid * 8]);
      GLDS(b_src1 + kn, &Bs[cur ^ 1][2048 + tid * 8]);
    }
    short8 af[2], bfr[4];
    #pragma unroll
    for (int i = 0; i < 2; i++) af[i] = ld_frag(&As[cur][aoff[i]]);
    #pragma unroll
    for (int j = 0; j < 4; j++) bfr[j] = ld_frag(&Bs[cur][boff[j]]);
    #pragma unroll
    for (int i = 0; i < 2; i++)
      #pragma unroll
      for (int j = 0; j < 4; j++)
        acc[i][j] = __builtin_amdgcn_mfma_f32_16x16x32_bf16(af[i], bfr[j], acc[i][j], 0, 0, 0);
    __syncthreads();            // drains vmcnt -> next buffer ready, this one reusable
    cur ^= 1;
  }

  // epilogue
  #pragma unroll
  for (int j = 0; j < 4; j++) {
    int col = cb + wn * 64 + j * 16 + l16;
    float bb = bias[col];
    #pragma unroll
    for (int i = 0; i < 2; i++) {
      #pragma unroll
      for (int r = 0; r < 4; r++) {
        int m = rb + wm * 32 + i * 16 + q4 * 4 + r;
        if (m < M) {
          float val = acc[i][j][r] + bb;
          if (OUT_BF16) ((unsigned short*)Cv)[(size_t)m * DM + col] = f2bf(val);
          else          ((float*)Cv)[(size_t)m * DM + col] = val;
        }
      }
    }
  }
}

// ---------------- Attention (unchanged) -------------------------------------
__global__ __launch_bounds__(256) void attn_kernel(
    const float* __restrict__ Q, const float* __restrict__ Kg,
    const float* __restrict__ Mask, const unsigned short* __restrict__ VV,
    float* __restrict__ Att, unsigned short* __restrict__ Out2)
{
  const int qt = blockIdx.x, h = blockIdx.y, b = blockIdx.z;
  const int tid = threadIdx.x;
  const int w = tid >> 6, lane = tid & 63, q4 = lane >> 4, l16 = lane & 15;
  const int qi0 = qt * 64;
  const int qb = w * 16;

  __shared__ unsigned short qsh[64][72];     // [q][d]   (bf16, pad: 144 B rows)
  __shared__ unsigned short ksh[64][72];     // [key][d]
  __shared__ unsigned short vshT[64][72];    // [d][key] (transposed)
  __shared__ unsigned short psh[4][16][72];  // per-wave P [q][key]

  // stage Q tile (query row qi reads q[b][qi+1][h*64 + d])
  {
    int qr = tid >> 2, d0 = (tid & 3) * 16;
    int qi = qi0 + qr;
    unsigned short tmp[16];
    if (qi < SL) {
      const float* src = Q + ((size_t)b * SS + qi + 1) * DM + h * DEPTH + d0;
      #pragma unroll
      for (int j = 0; j < 16; j += 4) {
        float4 f = *(const float4*)(src + j);
        tmp[j+0]=f2bf(f.x); tmp[j+1]=f2bf(f.y); tmp[j+2]=f2bf(f.z); tmp[j+3]=f2bf(f.w);
      }
    } else {
      #pragma unroll
      for (int j = 0; j < 16; j++) tmp[j] = 0;
    }
    *(uint4*)&qsh[qr][d0]     = *(uint4*)&tmp[0];
    *(uint4*)&qsh[qr][d0 + 8] = *(uint4*)&tmp[8];
  }

  auto stageK = [&](int kt) {
    int kr = tid >> 2, d0 = (tid & 3) * 16;
    int kj = kt * 64 + kr;
    unsigned short tmp[16];
    if (kj < SL) {
      const float* src = Kg + ((size_t)b * SS + kj) * DM + h * DEPTH + d0;
      #pragma unroll
      for (int j = 0; j < 16; j += 4) {
        float4 f = *(const float4*)(src + j);
        tmp[j+0]=f2bf(f.x); tmp[j+1]=f2bf(f.y); tmp[j+2]=f2bf(f.z); tmp[j+3]=f2bf(f.w);
      }
    } else {
      #pragma unroll
      for (int j = 0; j < 16; j++) tmp[j] = 0;
    }
    *(uint4*)&ksh[kr][d0]     = *(uint4*)&tmp[0];
    *(uint4*)&ksh[kr][d0 + 8] = *(uint4*)&tmp[8];
  };

  auto stageV = [&](int kt) {   // vshT[d][key_local], bf16 source in ws
    int d = tid & 63, k16 = (tid >> 6) * 16;
    unsigned short tmp[16];
    #pragma unroll
    for (int j = 0; j < 16; j++) {
      int kj = kt * 64 + k16 + j;
      tmp[j] = (kj < SL) ? VV[((size_t)b * SL + kj) * DM + h * DEPTH + d] : (unsigned short)0;
    }
    *(uint4*)&vshT[d][k16]     = *(uint4*)&tmp[0];
    *(uint4*)&vshT[d][k16 + 8] = *(uint4*)&tmp[8];
  };

  __syncthreads();

  // ---- pass 1: rowsums ----
  float rsv[4] = {0.f, 0.f, 0.f, 0.f};
  for (int kt = 0; kt < 16; kt++) {
    __syncthreads();
    stageK(kt);
    __syncthreads();
    #pragma unroll
    for (int nt = 0; nt < 4; nt++) {
      floatx4 s = (floatx4){0.f,0.f,0.f,0.f};
      s = __builtin_amdgcn_mfma_f32_16x16x32_bf16(
            ld_frag(&qsh[qb + l16][q4*8]), ld_frag(&ksh[nt*16 + l16][q4*8]), s, 0,0,0);
      s = __builtin_amdgcn_mfma_f32_16x16x32_bf16(
            ld_frag(&qsh[qb + l16][32 + q4*8]), ld_frag(&ksh[nt*16 + l16][32 + q4*8]), s, 0,0,0);
      int kj = kt * 64 + nt * 16 + l16;
      bool kv = kj < SL;
      int qi_b = qi0 + qb + q4 * 4;
      const float* mp = Mask + ((size_t)b * SL + qi_b) * SL + kj;
      #pragma unroll
      for (int r = 0; r < 4; r++) {
        int qi = qi_b + r;
        float mval = (kv && qi < SL) ? mp[(size_t)r * SL] : 0.f;
        float sv = fmaxf(s[r] * 0.125f, 0.f) + mval * (-1e9f);
        float p = kv ? __expf(sv) : 0.f;
        rsv[r] += p;
      }
    }
  }
  #pragma unroll
  for (int r = 0; r < 4; r++) {
    #pragma unroll
    for (int off = 1; off < 16; off <<= 1) rsv[r] += __shfl_xor(rsv[r], off, 64);
  }
  float inv[4];
  #pragma unroll
  for (int r = 0; r < 4; r++) inv[r] = 1.f / rsv[r];

  // ---- pass 2: att + PV ----
  floatx4 oacc[4];
  #pragma unroll
  for (int i = 0; i < 4; i++) oacc[i] = (floatx4){0.f,0.f,0.f,0.f};

  for (int kt = 0; kt < 16; kt++) {
    __syncthreads();
    stageK(kt);
    stageV(kt);
    __syncthreads();
    #pragma unroll
    for (int nt = 0; nt < 4; nt++) {
      floatx4 s = (floatx4){0.f,0.f,0.f,0.f};
      s = __builtin_amdgcn_mfma_f32_16x16x32_bf16(
            ld_frag(&qsh[qb + l16][q4*8]), ld_frag(&ksh[nt*16 + l16][q4*8]), s, 0,0,0);
      s = __builtin_amdgcn_mfma_f32_16x16x32_bf16(
            ld_frag(&qsh[qb + l16][32 + q4*8]), ld_frag(&ksh[nt*16 + l16][32 + q4*8]), s, 0,0,0);
      int kj = kt * 64 + nt * 16 + l16;
      bool kv = kj < SL;
      int qi_b = qi0 + qb + q4 * 4;
      const float* mp = Mask + ((size_t)b * SL + qi_b) * SL + kj;
      #pragma unroll
      for (int r = 0; r < 4; r++) {
        int qi = qi_b + r;
        bool qv = qi < SL;
        float mval = (kv && qv) ? mp[(size_t)r * SL] : 0.f;
        float sv = fmaxf(s[r] * 0.125f, 0.f) + mval * (-1e9f);
        float p = kv ? __expf(sv) : 0.f;
        float pn = p * inv[r];
        if (kv && qv)
          Att[(((size_t)(b * NUM_HEADS + h)) * SL + qi) * SL + kj] = pn;
        psh[w][q4 * 4 + r][nt * 16 + l16] = f2bf(pn);
      }
    }
    // PV: oacc(16q x 64d) += P(16q x 64k) @ V(64k x 64d)
    short8 pa0 = ld_frag(&psh[w][l16][q4 * 8]);
    short8 pa1 = ld_frag(&psh[w][l16][32 + q4 * 8]);
    #pragma unroll
    for (int nt2 = 0; nt2 < 4; nt2++) {
      oacc[nt2] = __builtin_amdgcn_mfma_f32_16x16x32_bf16(
                    pa0, ld_frag(&vshT[nt2*16 + l16][q4*8]), oacc[nt2], 0,0,0);
      oacc[nt2] = __builtin_amdgcn_mfma_f32_16x16x32_bf16(
                    pa1, ld_frag(&vshT[nt2*16 + l16][32 + q4*8]), oacc[nt2], 0,0,0);
    }
  }

  #pragma unroll
  for (int nt2 = 0; nt2 < 4; nt2++) {
    #pragma unroll
    for (int r = 0; r < 4; r++) {
      int qi = qi0 + qb + q4 * 4 + r;
      if (qi < SL)
        Out2[((size_t)b * SL + qi) * DM + h * DEPTH + nt2 * 16 + l16] = f2bf(oacc[nt2][r]);
    }
  }
}

extern "C" void kernel_launch(void* const* d_in, const int* in_sizes, int n_in,
                              void* d_out, int out_size, void* d_ws, size_t ws_size,
                              hipStream_t stream) {
  const float* v    = (const float*)d_in[0];
  const float* k    = (const float*)d_in[1];
  const float* q    = (const float*)d_in[2];
  const float* mask = (const float*)d_in[3];
  const float* Wv   = (const float*)d_in[4];
  const float* bv   = (const float*)d_in[5];
  const float* Wd   = (const float*)d_in[6];
  const float* bd   = (const float*)d_in[7];

  float* out = (float*)d_out;                                  // (4,1023,1024) fp32
  float* att = out + (size_t)M_ROWS * DM;                      // (4,16,1023,1023) fp32
  unsigned short* vv   = (unsigned short*)d_ws;                // bf16 (4,1023,1024)
  unsigned short* out2 = vv + (size_t)M_ROWS * DM;             // bf16 (4,1023,1024)

  // scratch inside the att region (dead until attn_kernel writes it):
  unsigned short* WvT = (unsigned short*)att;                  // bf16 [1024][1024] (n-major)
  unsigned short* vbf = WvT + (size_t)DM * DM;                 // bf16 (4,1023,1024)
  // after attn, vv is dead -> reuse its region for WdT:
  unsigned short* WdT = vv;                                    // bf16 [1024][1024]

  const int n8 = (M_ROWS * DM) / 8;                            // 523776

  // prep: v -> bf16, Wv -> transposed bf16
  f32_to_bf16_vec<<<dim3((n8 + 255) / 256), 256, 0, stream>>>(v, vbf, n8);
  transpose_to_bf16<<<dim3(16, 16), 256, 0, stream>>>(Wv, WvT);
  // vv = v @ Wv + bv   (bf16 GEMM, bf16 out in ws)
  gemm_bt<true><<<dim3(DM/128, (M_ROWS+63)/64), 256, 0, stream>>>(vbf, WvT, bv, (void*)vv, M_ROWS);
  // attention: att (fp32, d_out) + out2 (bf16, ws)  — overwrites the scratch
  attn_kernel<<<dim3(16, NUM_HEADS, BB), 256, 0, stream>>>(q, k, mask, vv, att, out2);
  // Wd -> transposed bf16 (vv region now dead)
  transpose_to_bf16<<<dim3(16, 16), 256, 0, stream>>>(Wd, WdT);
  // out = out2 @ Wd + bd  (bf16 GEMM, fp32 out)
  gemm_bt<false><<<dim3(DM/128, (M_ROWS+63)/64), 256, 0, stream>>>(out2, WdT, bd, (void*)out, M_ROWS);
}